// Round 6
// baseline (106.883 us; speedup 1.0000x reference)
//
#include <hip/hip_runtime.h>

#define WW 512
#define HH 512
#define CC 64
#define HW (HH*WW)
#define CPG 8                 // channels per gather thread
#define NGRP (CC/CPG)         // 8 channel groups
#define GXB 128               // gather blocks per group (grid-stride covers rest)

struct __align__(16) CState {
    float4 ewA;   // element weights for sample A (f1_2 from f2)
    float4 ewB;   // element weights for sample B (f2_1 from f1)
    int4   o;     // a0, a1, b0, b1 row offsets (clamped in-range)
    float  wgt;   // cycle-consistency weight (mask1-scaled)
    int    pix;   // source pixel
    int    pad0, pad1;
};

__device__ __forceinline__ void invert3(const float* __restrict__ m, float* o) {
    float a = m[0], b = m[1], c = m[2];
    float d = m[3], e = m[4], f = m[5];
    float g = m[6], h = m[7], i = m[8];
    float C11 =  (e*i - f*h);
    float C12 = -(d*i - f*g);
    float C13 =  (d*h - e*g);
    float C21 = -(b*i - c*h);
    float C22 =  (a*i - c*g);
    float C23 = -(a*h - b*g);
    float C31 =  (b*f - c*e);
    float C32 = -(a*f - c*d);
    float C33 =  (a*e - b*d);
    float det = a*C11 + b*C12 + c*C13;
    float id = 1.0f / det;
    o[0] = C11*id; o[1] = C21*id; o[2] = C31*id;
    o[3] = C12*id; o[4] = C22*id; o[5] = C32*id;
    o[6] = C13*id; o[7] = C23*id; o[8] = C33*id;
}

__device__ __forceinline__ void reproj_pt(
    float px, float py, float d,
    const float Kinv[9],
    const float* __restrict__ cf, const float* __restrict__ ct,
    const float* __restrict__ Kt,
    float& ox, float& oy)
{
    float cx = Kinv[0]*px + Kinv[1]*py + Kinv[2];
    float cy = Kinv[3]*px + Kinv[4]*py + Kinv[5];
    float cz = Kinv[6]*px + Kinv[7]*py + Kinv[8];
    cx *= d; cy *= d; cz *= d;
    float wx = cf[0]*cx + cf[1]*cy + cf[2]*cz + cf[3];
    float wy = cf[4]*cx + cf[5]*cy + cf[6]*cz + cf[7];
    float wz = cf[8]*cx + cf[9]*cy + cf[10]*cz + cf[11];
    float qx = wx - ct[3], qy = wy - ct[7], qz = wz - ct[11];
    float ax = ct[0]*qx + ct[4]*qy + ct[8]*qz;
    float ay = ct[1]*qx + ct[5]*qy + ct[9]*qz;
    float az = ct[2]*qx + ct[6]*qy + ct[10]*qz;
    float p0 = Kt[0]*ax + Kt[1]*ay + Kt[2]*az;
    float p1 = Kt[3]*ax + Kt[4]*ay + Kt[5]*az;
    float p2 = Kt[6]*ax + Kt[7]*ay + Kt[8]*az;
    float zs = (fabsf(p2) > 1e-6f) ? p2 : 1e-6f;
    float u = p0 / zs;
    float v = p1 / zs;
    ox = u / 512.0f * 2.0f - 1.0f;
    oy = v / 512.0f * 2.0f - 1.0f;
}

// Bilinear state (verified absmax 0.0 in R4/R5): two clamped row offsets,
// 4 element-weights matched to elements (xc, xc+1) on rows y0, y0+1; OOB
// corners carry zero weight.
__device__ __forceinline__ void bilin_state(
    float lx, float ly, float4& ew, int& o0, int& o1)
{
    float xf = (lx + 1.0f) * 256.0f - 0.5f;
    float yf = (ly + 1.0f) * 256.0f - 0.5f;
    float x0 = floorf(xf), y0 = floorf(yf);
    float wx = xf - x0, wy = yf - y0;
    x0 = fminf(fmaxf(x0, -1e8f), 1e8f);
    y0 = fminf(fmaxf(y0, -1e8f), 1e8f);
    int x0i = (int)x0, y0i = (int)y0;

    float vx0 = (x0i >= 0 && x0i < WW) ? 1.0f : 0.0f;
    float vx1 = (x0i + 1 >= 0 && x0i + 1 < WW) ? 1.0f : 0.0f;
    float vy0 = (y0i >= 0 && y0i < HH) ? 1.0f : 0.0f;
    float vy1 = (y0i + 1 >= 0 && y0i + 1 < HH) ? 1.0f : 0.0f;
    float w00 = (1.0f - wx) * (1.0f - wy) * vx0 * vy0;
    float w10 = wx * (1.0f - wy) * vx1 * vy0;
    float w01 = (1.0f - wx) * wy * vx0 * vy1;
    float w11 = wx * wy * vx1 * vy1;

    int xc = min(max(x0i, 0), WW - 2);
    float e0r0 = (xc == x0i) ? w00 : ((xc == x0i + 1) ? w10 : 0.0f);
    float e1r0 = (xc + 1 == x0i + 1) ? w10 : ((xc + 1 == x0i) ? w00 : 0.0f);
    float e0r1 = (xc == x0i) ? w01 : ((xc == x0i + 1) ? w11 : 0.0f);
    float e1r1 = (xc + 1 == x0i + 1) ? w11 : ((xc + 1 == x0i) ? w01 : 0.0f);
    ew = make_float4(e0r0, e1r0, e0r1, e1r1);
    o0 = min(max(y0i, 0), HH - 1) * WW + xc;
    o1 = min(max(y0i + 1, 0), HH - 1) * WW + xc;
}

// ---------- K1: per-pixel setup; passing pixels appended to compact list ----------
__global__ __launch_bounds__(256) void setup_kernel(
    const float* __restrict__ d1p, const float* __restrict__ d2p,
    const float* __restrict__ m1p,
    const float* __restrict__ K1, const float* __restrict__ K2,
    const float* __restrict__ cw1, const float* __restrict__ cw2,
    int* __restrict__ cnt, CState* __restrict__ comp)
{
    int pix = blockIdx.x * 256 + threadIdx.x;
    int j = pix & (WW - 1);
    int i = pix >> 9;
    float Ki1[9], Ki2[9];
    invert3(K1, Ki1);
    invert3(K2, Ki2);
    float px = j + 0.5f, py = i + 0.5f;

    float l12x, l12y, l21x, l21y;
    reproj_pt(px, py, d1p[pix], Ki1, cw1, cw2, K2, l12x, l12y);
    reproj_pt(px, py, d2p[pix], Ki2, cw2, cw1, K1, l21x, l21y);

    float4 ewA; int a0, a1;
    bilin_state(l12x, l12y, ewA, a0, a1);

    // l1_2_1 = bilinear sample of the l2_1 field at l1_2, recomputing the
    // field at the 4 corner pixels (exact).
    float vx = 0.0f, vy = 0.0f;
    {
        int offs[2] = {a0, a1};
        #pragma unroll
        for (int r = 0; r < 2; ++r) {
            #pragma unroll
            for (int kx = 0; kx < 2; ++kx) {
                int off = offs[r] + kx;
                float w = (r == 0) ? (kx ? ewA.y : ewA.x) : (kx ? ewA.w : ewA.z);
                if (w != 0.0f) {
                    int cj = off & (WW - 1), ci = off >> 9;
                    float cxv, cyv;
                    reproj_pt(cj + 0.5f, ci + 0.5f, d2p[off], Ki2, cw2, cw1, K1, cxv, cyv);
                    vx += w * cxv;
                    vy += w * cyv;
                }
            }
        }
    }
    float gx = (j + 0.5f) / 512.0f * 2.0f - 1.0f;
    float gy = (i + 0.5f) / 512.0f * 2.0f - 1.0f;
    float ddx = gx - vx, ddy = gy - vy;
    float dist = sqrtf(ddx * ddx + ddy * ddy);
    float wgt = (dist < 0.0025f) ? m1p[pix] : 0.0f;

    if (wgt != 0.0f) {
        float4 ewB; int b0, b1;
        bilin_state(l21x, l21y, ewB, b0, b1);
        int slot = atomicAdd(cnt, 1);
        CState s;
        s.ewA = ewA; s.ewB = ewB;
        s.o = make_int4(a0, a1, b0, b1);
        s.wgt = wgt; s.pix = pix; s.pad0 = 0; s.pad1 = 0;
        comp[slot] = s;
    }
}

// ---------- K2: gather over compacted list; blockIdx.y = channel group ----------
__global__ __launch_bounds__(256) void gather_kernel(
    const float* __restrict__ f1, const float* __restrict__ f2,
    const int* __restrict__ cnt, const CState* __restrict__ comp,
    float* __restrict__ out)
{
    int count = cnt[0];
    int tid = blockIdx.x * 256 + threadIdx.x;
    const float* F1b = f1 + (size_t)blockIdx.y * CPG * HW;
    const float* F2b = f2 + (size_t)blockIdx.y * CPG * HW;

    float lsum = 0.0f;
    for (int s = tid; s < count; s += GXB * 256) {
        const float4* c4 = (const float4*)&comp[s];
        float4 ewA = c4[0];
        float4 ewB = c4[1];
        int4 o = ((const int4*)c4)[2];
        float4 t = c4[3];
        float wgt = t.x;
        int pix = __float_as_int(t.y);

        const float* F1 = F1b;
        const float* F2 = F2b;
        float acc = 0.0f;
        #pragma unroll
        for (int c = 0; c < CPG; ++c) {
            float s1 = ewA.x*F2[o.x] + ewA.y*F2[o.x+1] + ewA.z*F2[o.y] + ewA.w*F2[o.y+1];
            float s2 = ewB.x*F1[o.z] + ewB.y*F1[o.z+1] + ewB.z*F1[o.w] + ewB.w*F1[o.w+1];
            float e1 = F1[pix] - s1;
            float e2 = F2[pix] - s2;
            acc += e1 * e1 + e2 * e2;
            F1 += HW;
            F2 += HW;
        }
        lsum += wgt * acc;
    }

    #pragma unroll
    for (int off = 32; off > 0; off >>= 1)
        lsum += __shfl_down(lsum, off);
    __shared__ float sred[4];
    int wave = threadIdx.x >> 6;
    if ((threadIdx.x & 63) == 0) sred[wave] = lsum;
    __syncthreads();
    if (threadIdx.x == 0) {
        float tt = (sred[0] + sred[1]) + (sred[2] + sred[3]);
        if (tt != 0.0f) atomicAdd(out, tt * (1.0f / 262144.0f));
    }
}

// ---------- fallback: monolithic kernel (only if ws too small) ----------
__global__ __launch_bounds__(256) void mono_kernel(
    const float* __restrict__ f1, const float* __restrict__ f2,
    const float* __restrict__ d1p, const float* __restrict__ d2p,
    const float* __restrict__ m1p,
    const float* __restrict__ K1, const float* __restrict__ K2,
    const float* __restrict__ cw1, const float* __restrict__ cw2,
    float* __restrict__ out)
{
    int pix = blockIdx.x * 256 + threadIdx.x;
    int j = pix & (WW - 1);
    int i = pix >> 9;
    float Ki1[9], Ki2[9];
    invert3(K1, Ki1);
    invert3(K2, Ki2);
    float px = j + 0.5f, py = i + 0.5f;

    float l12x, l12y, l21x, l21y;
    reproj_pt(px, py, d1p[pix], Ki1, cw1, cw2, K2, l12x, l12y);
    reproj_pt(px, py, d2p[pix], Ki2, cw2, cw1, K1, l21x, l21y);

    float4 ewA; int a0, a1;
    bilin_state(l12x, l12y, ewA, a0, a1);

    float vx = 0.0f, vy = 0.0f;
    {
        int offs[2] = {a0, a1};
        #pragma unroll
        for (int r = 0; r < 2; ++r) {
            #pragma unroll
            for (int kx = 0; kx < 2; ++kx) {
                int off = offs[r] + kx;
                float w = (r == 0) ? (kx ? ewA.y : ewA.x) : (kx ? ewA.w : ewA.z);
                if (w != 0.0f) {
                    int cj = off & (WW - 1), ci = off >> 9;
                    float cxv, cyv;
                    reproj_pt(cj + 0.5f, ci + 0.5f, d2p[off], Ki2, cw2, cw1, K1, cxv, cyv);
                    vx += w * cxv;
                    vy += w * cyv;
                }
            }
        }
    }
    float gx = (j + 0.5f) / 512.0f * 2.0f - 1.0f;
    float gy = (i + 0.5f) / 512.0f * 2.0f - 1.0f;
    float ddx = gx - vx, ddy = gy - vy;
    float dist = sqrtf(ddx * ddx + ddy * ddy);
    float wgt = (dist < 0.0025f) ? m1p[pix] : 0.0f;

    float lsum = 0.0f;
    if (wgt != 0.0f) {
        float4 ewB; int b0, b1;
        bilin_state(l21x, l21y, ewB, b0, b1);
        float acc = 0.0f;
        const float* F1 = f1;
        const float* F2 = f2;
        for (int c = 0; c < CC; ++c) {
            float s1 = ewA.x*F2[a0] + ewA.y*F2[a0+1] + ewA.z*F2[a1] + ewA.w*F2[a1+1];
            float s2 = ewB.x*F1[b0] + ewB.y*F1[b0+1] + ewB.z*F1[b1] + ewB.w*F1[b1+1];
            float e1 = F1[pix] - s1;
            float e2 = F2[pix] - s2;
            acc += e1 * e1 + e2 * e2;
            F1 += HW; F2 += HW;
        }
        lsum = wgt * acc;
    }

    #pragma unroll
    for (int off = 32; off > 0; off >>= 1)
        lsum += __shfl_down(lsum, off);
    __shared__ float sred[4];
    if ((threadIdx.x & 63) == 0) sred[threadIdx.x >> 6] = lsum;
    __syncthreads();
    if (threadIdx.x == 0) {
        float t = (sred[0] + sred[1]) + (sred[2] + sred[3]);
        atomicAdd(out, t * (1.0f / 262144.0f));
    }
}

extern "C" void kernel_launch(void* const* d_in, const int* in_sizes, int n_in,
                              void* d_out, int out_size, void* d_ws, size_t ws_size,
                              hipStream_t stream) {
    const float* f1  = (const float*)d_in[0];
    const float* f2  = (const float*)d_in[1];
    const float* dp1 = (const float*)d_in[4];
    const float* dp2 = (const float*)d_in[5];
    const float* m1  = (const float*)d_in[6];
    const float* K1  = (const float*)d_in[8];
    const float* K2  = (const float*)d_in[9];
    const float* c1  = (const float*)d_in[10];
    const float* c2  = (const float*)d_in[11];

    float* out = (float*)d_out;
    hipMemsetAsync(out, 0, sizeof(float), stream);

    const size_t need = 64 + (size_t)HW * sizeof(CState);  // ~16.8 MB
    if (ws_size >= need) {
        int* cnt = (int*)d_ws;
        CState* comp = (CState*)((char*)d_ws + 64);
        hipMemsetAsync(cnt, 0, sizeof(int), stream);
        setup_kernel<<<HW / 256, 256, 0, stream>>>(
            dp1, dp2, m1, K1, K2, c1, c2, cnt, comp);
        gather_kernel<<<dim3(GXB, NGRP), 256, 0, stream>>>(
            f1, f2, cnt, comp, out);
    } else {
        mono_kernel<<<HW / 256, 256, 0, stream>>>(
            f1, f2, dp1, dp2, m1, K1, K2, c1, c2, out);
    }
}

// Round 7
// 74.392 us; speedup vs baseline: 1.4368x; 1.4368x over previous
//
#include <hip/hip_runtime.h>

#define WW 512
#define HH 512
#define CC 64
#define HW (HH*WW)

struct __align__(16) LItem {
    float4 ewA;   // element weights for sample A (f1_2 from f2)
    float4 ewB;   // element weights for sample B (f2_1 from f1)
    int4   o;     // a0, a1, b0, b1 row offsets (clamped in-range)
    float  wgt;
    int    pix;
    int    pad0, pad1;
};

__device__ __forceinline__ void invert3(const float* __restrict__ m, float* o) {
    float a = m[0], b = m[1], c = m[2];
    float d = m[3], e = m[4], f = m[5];
    float g = m[6], h = m[7], i = m[8];
    float C11 =  (e*i - f*h);
    float C12 = -(d*i - f*g);
    float C13 =  (d*h - e*g);
    float C21 = -(b*i - c*h);
    float C22 =  (a*i - c*g);
    float C23 = -(a*h - b*g);
    float C31 =  (b*f - c*e);
    float C32 = -(a*f - c*d);
    float C33 =  (a*e - b*d);
    float det = a*C11 + b*C12 + c*C13;
    float id = 1.0f / det;
    o[0] = C11*id; o[1] = C21*id; o[2] = C31*id;
    o[3] = C12*id; o[4] = C22*id; o[5] = C32*id;
    o[6] = C13*id; o[7] = C23*id; o[8] = C33*id;
}

__device__ __forceinline__ void reproj_pt(
    float px, float py, float d,
    const float Kinv[9],
    const float* __restrict__ cf, const float* __restrict__ ct,
    const float* __restrict__ Kt,
    float& ox, float& oy)
{
    float cx = Kinv[0]*px + Kinv[1]*py + Kinv[2];
    float cy = Kinv[3]*px + Kinv[4]*py + Kinv[5];
    float cz = Kinv[6]*px + Kinv[7]*py + Kinv[8];
    cx *= d; cy *= d; cz *= d;
    float wx = cf[0]*cx + cf[1]*cy + cf[2]*cz + cf[3];
    float wy = cf[4]*cx + cf[5]*cy + cf[6]*cz + cf[7];
    float wz = cf[8]*cx + cf[9]*cy + cf[10]*cz + cf[11];
    float qx = wx - ct[3], qy = wy - ct[7], qz = wz - ct[11];
    float ax = ct[0]*qx + ct[4]*qy + ct[8]*qz;
    float ay = ct[1]*qx + ct[5]*qy + ct[9]*qz;
    float az = ct[2]*qx + ct[6]*qy + ct[10]*qz;
    float p0 = Kt[0]*ax + Kt[1]*ay + Kt[2]*az;
    float p1 = Kt[3]*ax + Kt[4]*ay + Kt[5]*az;
    float p2 = Kt[6]*ax + Kt[7]*ay + Kt[8]*az;
    float zs = (fabsf(p2) > 1e-6f) ? p2 : 1e-6f;
    float u = p0 / zs;
    float v = p1 / zs;
    ox = u / 512.0f * 2.0f - 1.0f;
    oy = v / 512.0f * 2.0f - 1.0f;
}

// Bilinear state (verified absmax 0.0 in R4-R6): two clamped row offsets,
// 4 element-weights matched to elements (xc, xc+1) on rows y0, y0+1; OOB
// corners carry zero weight.
__device__ __forceinline__ void bilin_state(
    float lx, float ly, float4& ew, int& o0, int& o1)
{
    float xf = (lx + 1.0f) * 256.0f - 0.5f;
    float yf = (ly + 1.0f) * 256.0f - 0.5f;
    float x0 = floorf(xf), y0 = floorf(yf);
    float wx = xf - x0, wy = yf - y0;
    x0 = fminf(fmaxf(x0, -1e8f), 1e8f);
    y0 = fminf(fmaxf(y0, -1e8f), 1e8f);
    int x0i = (int)x0, y0i = (int)y0;

    float vx0 = (x0i >= 0 && x0i < WW) ? 1.0f : 0.0f;
    float vx1 = (x0i + 1 >= 0 && x0i + 1 < WW) ? 1.0f : 0.0f;
    float vy0 = (y0i >= 0 && y0i < HH) ? 1.0f : 0.0f;
    float vy1 = (y0i + 1 >= 0 && y0i + 1 < HH) ? 1.0f : 0.0f;
    float w00 = (1.0f - wx) * (1.0f - wy) * vx0 * vy0;
    float w10 = wx * (1.0f - wy) * vx1 * vy0;
    float w01 = (1.0f - wx) * wy * vx0 * vy1;
    float w11 = wx * wy * vx1 * vy1;

    int xc = min(max(x0i, 0), WW - 2);
    float e0r0 = (xc == x0i) ? w00 : ((xc == x0i + 1) ? w10 : 0.0f);
    float e1r0 = (xc + 1 == x0i + 1) ? w10 : ((xc + 1 == x0i) ? w00 : 0.0f);
    float e0r1 = (xc == x0i) ? w01 : ((xc == x0i + 1) ? w11 : 0.0f);
    float e1r1 = (xc + 1 == x0i + 1) ? w11 : ((xc + 1 == x0i) ? w01 : 0.0f);
    ew = make_float4(e0r0, e1r0, e0r1, e1r1);
    o0 = min(max(y0i, 0), HH - 1) * WW + xc;
    o1 = min(max(y0i + 1, 0), HH - 1) * WW + xc;
}

// Fused: per-pixel setup -> block-local LDS compaction -> wave-per-item,
// channel-per-lane gather -> block reduce -> one atomicAdd per block.
__global__ __launch_bounds__(256) void fused_kernel(
    const float* __restrict__ f1, const float* __restrict__ f2,
    const float* __restrict__ d1p, const float* __restrict__ d2p,
    const float* __restrict__ m1p,
    const float* __restrict__ K1, const float* __restrict__ K2,
    const float* __restrict__ cw1, const float* __restrict__ cw2,
    float* __restrict__ out)
{
    __shared__ LItem items[256];   // 16 KB
    __shared__ int nitems;
    __shared__ float sred[4];

    int tid  = threadIdx.x;
    int wave = tid >> 6;
    int lane = tid & 63;
    int pix  = blockIdx.x * 256 + tid;
    int j = pix & (WW - 1);
    int i = pix >> 9;

    if (tid == 0) nitems = 0;

    // ---------------- phase 1: setup (validated arithmetic) ----------------
    float Ki1[9], Ki2[9];
    invert3(K1, Ki1);
    invert3(K2, Ki2);
    float px = j + 0.5f, py = i + 0.5f;

    float l12x, l12y, l21x, l21y;
    reproj_pt(px, py, d1p[pix], Ki1, cw1, cw2, K2, l12x, l12y);
    reproj_pt(px, py, d2p[pix], Ki2, cw2, cw1, K1, l21x, l21y);

    float4 ewA; int a0, a1;
    bilin_state(l12x, l12y, ewA, a0, a1);

    // l1_2_1: bilinear sample of the l2_1 field at l1_2 via exact corner
    // recompute from depth2.
    float vx = 0.0f, vy = 0.0f;
    {
        int offs[2] = {a0, a1};
        #pragma unroll
        for (int r = 0; r < 2; ++r) {
            #pragma unroll
            for (int kx = 0; kx < 2; ++kx) {
                int off = offs[r] + kx;
                float w = (r == 0) ? (kx ? ewA.y : ewA.x) : (kx ? ewA.w : ewA.z);
                if (w != 0.0f) {
                    int cj = off & (WW - 1), ci = off >> 9;
                    float cxv, cyv;
                    reproj_pt(cj + 0.5f, ci + 0.5f, d2p[off], Ki2, cw2, cw1, K1, cxv, cyv);
                    vx += w * cxv;
                    vy += w * cyv;
                }
            }
        }
    }
    float gx = (j + 0.5f) / 512.0f * 2.0f - 1.0f;
    float gy = (i + 0.5f) / 512.0f * 2.0f - 1.0f;
    float ddx = gx - vx, ddy = gy - vy;
    float dist = sqrtf(ddx * ddx + ddy * ddy);
    float wgt = (dist < 0.0025f) ? m1p[pix] : 0.0f;

    __syncthreads();   // nitems = 0 visible

    if (wgt != 0.0f) {
        float4 ewB; int b0, b1;
        bilin_state(l21x, l21y, ewB, b0, b1);
        int slot = atomicAdd(&nitems, 1);   // LDS atomic
        LItem s;
        s.ewA = ewA; s.ewB = ewB;
        s.o = make_int4(a0, a1, b0, b1);
        s.wgt = wgt; s.pix = pix; s.pad0 = 0; s.pad1 = 0;
        items[slot] = s;
    }
    __syncthreads();

    // -------- phase 2: wave-per-item, lane = channel --------
    int n = nitems;
    const float* F1 = f1 + (size_t)lane * HW;   // lane's channel plane
    const float* F2 = f2 + (size_t)lane * HW;

    float lsum = 0.0f;
    for (int it = wave; it < n; it += 4) {
        float4 eA = items[it].ewA;
        float4 eB = items[it].ewB;
        int4   o  = items[it].o;
        float  w  = items[it].wgt;
        int    p  = items[it].pix;

        float a0v = F2[o.x], a1v = F2[o.x + 1];
        float a2v = F2[o.y], a3v = F2[o.y + 1];
        float b0v = F1[o.z], b1v = F1[o.z + 1];
        float b2v = F1[o.w], b3v = F1[o.w + 1];
        float p1v = F1[p],   p2v = F2[p];

        float s1 = eA.x * a0v + eA.y * a1v + eA.z * a2v + eA.w * a3v;
        float s2 = eB.x * b0v + eB.y * b1v + eB.z * b2v + eB.w * b3v;
        float e1 = p1v - s1;
        float e2 = p2v - s2;
        lsum += w * (e1 * e1 + e2 * e2);
    }

    // -------- reduce: wave shuffle -> LDS -> one atomic per block --------
    #pragma unroll
    for (int off = 32; off > 0; off >>= 1)
        lsum += __shfl_down(lsum, off);
    if (lane == 0) sred[wave] = lsum;
    __syncthreads();
    if (tid == 0) {
        float t = (sred[0] + sred[1]) + (sred[2] + sred[3]);
        if (t != 0.0f) atomicAdd(out, t * (1.0f / 262144.0f));
    }
}

extern "C" void kernel_launch(void* const* d_in, const int* in_sizes, int n_in,
                              void* d_out, int out_size, void* d_ws, size_t ws_size,
                              hipStream_t stream) {
    const float* f1  = (const float*)d_in[0];
    const float* f2  = (const float*)d_in[1];
    const float* dp1 = (const float*)d_in[4];
    const float* dp2 = (const float*)d_in[5];
    const float* m1  = (const float*)d_in[6];
    const float* K1  = (const float*)d_in[8];
    const float* K2  = (const float*)d_in[9];
    const float* c1  = (const float*)d_in[10];
    const float* c2  = (const float*)d_in[11];

    float* out = (float*)d_out;
    hipMemsetAsync(out, 0, sizeof(float), stream);
    fused_kernel<<<HW / 256, 256, 0, stream>>>(
        f1, f2, dp1, dp2, m1, K1, K2, c1, c2, out);
}

// Round 8
// 53.650 us; speedup vs baseline: 1.9922x; 1.3866x over previous
//
#include <hip/hip_runtime.h>

#define WW 512
#define HH 512
#define CC 64
#define HW (HH*WW)
#define PPB 128               // pixels per block
#define NBLK (HW/PPB)         // 2048 blocks

struct __align__(16) LItem {
    float4 ewA;   // element weights for sample A (f1_2 from f2)
    float4 ewB;   // element weights for sample B (f2_1 from f1)
    int4   o;     // a0, a1, b0, b1 row offsets (clamped in-range)
    float  wgt;
    int    pix;
    int    pad0, pad1;
};

__device__ __forceinline__ void invert3(const float* __restrict__ m, float* o) {
    float a = m[0], b = m[1], c = m[2];
    float d = m[3], e = m[4], f = m[5];
    float g = m[6], h = m[7], i = m[8];
    float C11 =  (e*i - f*h);
    float C12 = -(d*i - f*g);
    float C13 =  (d*h - e*g);
    float C21 = -(b*i - c*h);
    float C22 =  (a*i - c*g);
    float C23 = -(a*h - b*g);
    float C31 =  (b*f - c*e);
    float C32 = -(a*f - c*d);
    float C33 =  (a*e - b*d);
    float det = a*C11 + b*C12 + c*C13;
    float id = 1.0f / det;
    o[0] = C11*id; o[1] = C21*id; o[2] = C31*id;
    o[3] = C12*id; o[4] = C22*id; o[5] = C32*id;
    o[6] = C13*id; o[7] = C23*id; o[8] = C33*id;
}

__device__ __forceinline__ void reproj_pt(
    float px, float py, float d,
    const float Kinv[9],
    const float* __restrict__ cf, const float* __restrict__ ct,
    const float* __restrict__ Kt,
    float& ox, float& oy)
{
    float cx = Kinv[0]*px + Kinv[1]*py + Kinv[2];
    float cy = Kinv[3]*px + Kinv[4]*py + Kinv[5];
    float cz = Kinv[6]*px + Kinv[7]*py + Kinv[8];
    cx *= d; cy *= d; cz *= d;
    float wx = cf[0]*cx + cf[1]*cy + cf[2]*cz + cf[3];
    float wy = cf[4]*cx + cf[5]*cy + cf[6]*cz + cf[7];
    float wz = cf[8]*cx + cf[9]*cy + cf[10]*cz + cf[11];
    float qx = wx - ct[3], qy = wy - ct[7], qz = wz - ct[11];
    float ax = ct[0]*qx + ct[4]*qy + ct[8]*qz;
    float ay = ct[1]*qx + ct[5]*qy + ct[9]*qz;
    float az = ct[2]*qx + ct[6]*qy + ct[10]*qz;
    float p0 = Kt[0]*ax + Kt[1]*ay + Kt[2]*az;
    float p1 = Kt[3]*ax + Kt[4]*ay + Kt[5]*az;
    float p2 = Kt[6]*ax + Kt[7]*ay + Kt[8]*az;
    float zs = (fabsf(p2) > 1e-6f) ? p2 : 1e-6f;
    float u = p0 / zs;
    float v = p1 / zs;
    ox = u / 512.0f * 2.0f - 1.0f;
    oy = v / 512.0f * 2.0f - 1.0f;
}

// Bilinear state (verified absmax 0.0 in R4-R7): two clamped row offsets,
// 4 element-weights matched to elements (xc, xc+1) on rows y0, y0+1; OOB
// corners carry zero weight.
__device__ __forceinline__ void bilin_state(
    float lx, float ly, float4& ew, int& o0, int& o1)
{
    float xf = (lx + 1.0f) * 256.0f - 0.5f;
    float yf = (ly + 1.0f) * 256.0f - 0.5f;
    float x0 = floorf(xf), y0 = floorf(yf);
    float wx = xf - x0, wy = yf - y0;
    x0 = fminf(fmaxf(x0, -1e8f), 1e8f);
    y0 = fminf(fmaxf(y0, -1e8f), 1e8f);
    int x0i = (int)x0, y0i = (int)y0;

    float vx0 = (x0i >= 0 && x0i < WW) ? 1.0f : 0.0f;
    float vx1 = (x0i + 1 >= 0 && x0i + 1 < WW) ? 1.0f : 0.0f;
    float vy0 = (y0i >= 0 && y0i < HH) ? 1.0f : 0.0f;
    float vy1 = (y0i + 1 >= 0 && y0i + 1 < HH) ? 1.0f : 0.0f;
    float w00 = (1.0f - wx) * (1.0f - wy) * vx0 * vy0;
    float w10 = wx * (1.0f - wy) * vx1 * vy0;
    float w01 = (1.0f - wx) * wy * vx0 * vy1;
    float w11 = wx * wy * vx1 * vy1;

    int xc = min(max(x0i, 0), WW - 2);
    float e0r0 = (xc == x0i) ? w00 : ((xc == x0i + 1) ? w10 : 0.0f);
    float e1r0 = (xc + 1 == x0i + 1) ? w10 : ((xc + 1 == x0i) ? w00 : 0.0f);
    float e0r1 = (xc == x0i) ? w01 : ((xc == x0i + 1) ? w11 : 0.0f);
    float e1r1 = (xc + 1 == x0i + 1) ? w11 : ((xc + 1 == x0i) ? w01 : 0.0f);
    ew = make_float4(e0r0, e1r0, e0r1, e1r1);
    o0 = min(max(y0i, 0), HH - 1) * WW + xc;
    o1 = min(max(y0i + 1, 0), HH - 1) * WW + xc;
}

// Fused: 128 pixels/block (setup by tid<128) -> LDS compaction ->
// 4 waves gather (lane = channel, dual-item batches) -> block reduce.
__global__ __launch_bounds__(256) void fused_kernel(
    const float* __restrict__ f1, const float* __restrict__ f2,
    const float* __restrict__ d1p, const float* __restrict__ d2p,
    const float* __restrict__ m1p,
    const float* __restrict__ K1, const float* __restrict__ K2,
    const float* __restrict__ cw1, const float* __restrict__ cw2,
    float* __restrict__ out)
{
    __shared__ LItem items[PPB];   // 8 KB
    __shared__ int nitems;
    __shared__ float sred[4];

    // XCD-chunked swizzle: contiguous pixel ranges land on one XCD's L2.
    int bid = (int)(blockIdx.x & 7) * (NBLK / 8) + (int)(blockIdx.x >> 3);

    int tid  = threadIdx.x;
    int wave = tid >> 6;
    int lane = tid & 63;
    bool active = tid < PPB;
    int pix  = bid * PPB + (tid & (PPB - 1));
    int j = pix & (WW - 1);
    int i = pix >> 9;

    if (tid == 0) nitems = 0;

    // ---------------- phase 1: setup (validated arithmetic) ----------------
    float wgt = 0.0f;
    float4 ewA; int a0 = 0, a1 = 0;
    float l21x = 0.0f, l21y = 0.0f;
    if (active) {
        float Ki1[9], Ki2[9];
        invert3(K1, Ki1);
        invert3(K2, Ki2);
        float px = j + 0.5f, py = i + 0.5f;

        float l12x, l12y;
        reproj_pt(px, py, d1p[pix], Ki1, cw1, cw2, K2, l12x, l12y);
        reproj_pt(px, py, d2p[pix], Ki2, cw2, cw1, K1, l21x, l21y);

        bilin_state(l12x, l12y, ewA, a0, a1);

        // l1_2_1: bilinear sample of the l2_1 field at l1_2 via exact
        // corner recompute from depth2.
        float vx = 0.0f, vy = 0.0f;
        int offs[2] = {a0, a1};
        #pragma unroll
        for (int r = 0; r < 2; ++r) {
            #pragma unroll
            for (int kx = 0; kx < 2; ++kx) {
                int off = offs[r] + kx;
                float w = (r == 0) ? (kx ? ewA.y : ewA.x) : (kx ? ewA.w : ewA.z);
                if (w != 0.0f) {
                    int cj = off & (WW - 1), ci = off >> 9;
                    float cxv, cyv;
                    reproj_pt(cj + 0.5f, ci + 0.5f, d2p[off], Ki2, cw2, cw1, K1, cxv, cyv);
                    vx += w * cxv;
                    vy += w * cyv;
                }
            }
        }
        float gx = (j + 0.5f) / 512.0f * 2.0f - 1.0f;
        float gy = (i + 0.5f) / 512.0f * 2.0f - 1.0f;
        float ddx = gx - vx, ddy = gy - vy;
        float dist = sqrtf(ddx * ddx + ddy * ddy);
        wgt = (dist < 0.0025f) ? m1p[pix] : 0.0f;
    }

    __syncthreads();   // nitems = 0 visible

    if (active && wgt != 0.0f) {
        float4 ewB; int b0, b1;
        bilin_state(l21x, l21y, ewB, b0, b1);
        int slot = atomicAdd(&nitems, 1);   // LDS atomic
        LItem s;
        s.ewA = ewA; s.ewB = ewB;
        s.o = make_int4(a0, a1, b0, b1);
        s.wgt = wgt; s.pix = pix; s.pad0 = 0; s.pad1 = 0;
        items[slot] = s;
    }
    __syncthreads();

    // -------- phase 2: wave-per-item (lane = channel), dual-item batches --------
    int n = nitems;
    const float* F1 = f1 + (size_t)lane * HW;   // lane's channel plane
    const float* F2 = f2 + (size_t)lane * HW;

    float lsum = 0.0f;
    for (int it = wave; it < n; it += 8) {
        int itB = it + 4;
        bool hasB = itB < n;
        int itBc = hasB ? itB : it;

        float4 eA0 = items[it].ewA;
        float4 eB0 = items[it].ewB;
        int4   o0v = items[it].o;
        float  w0  = items[it].wgt;
        int    p0  = items[it].pix;
        float4 eA1 = items[itBc].ewA;
        float4 eB1 = items[itBc].ewB;
        int4   o1v = items[itBc].o;
        float  w1  = hasB ? items[itBc].wgt : 0.0f;
        int    p1  = items[itBc].pix;

        // issue all 20 loads before consuming
        float xa0 = F2[o0v.x], xa1 = F2[o0v.x + 1];
        float xa2 = F2[o0v.y], xa3 = F2[o0v.y + 1];
        float xb0 = F1[o0v.z], xb1 = F1[o0v.z + 1];
        float xb2 = F1[o0v.w], xb3 = F1[o0v.w + 1];
        float xp1 = F1[p0],    xp2 = F2[p0];
        float ya0 = F2[o1v.x], ya1 = F2[o1v.x + 1];
        float ya2 = F2[o1v.y], ya3 = F2[o1v.y + 1];
        float yb0 = F1[o1v.z], yb1 = F1[o1v.z + 1];
        float yb2 = F1[o1v.w], yb3 = F1[o1v.w + 1];
        float yp1 = F1[p1],    yp2 = F2[p1];

        float s1x = eA0.x*xa0 + eA0.y*xa1 + eA0.z*xa2 + eA0.w*xa3;
        float s2x = eB0.x*xb0 + eB0.y*xb1 + eB0.z*xb2 + eB0.w*xb3;
        float e1x = xp1 - s1x;
        float e2x = xp2 - s2x;
        float s1y = eA1.x*ya0 + eA1.y*ya1 + eA1.z*ya2 + eA1.w*ya3;
        float s2y = eB1.x*yb0 + eB1.y*yb1 + eB1.z*yb2 + eB1.w*yb3;
        float e1y = yp1 - s1y;
        float e2y = yp2 - s2y;
        lsum += w0 * (e1x * e1x + e2x * e2x) + w1 * (e1y * e1y + e2y * e2y);
    }

    // -------- reduce: wave shuffle -> LDS -> one atomic per block --------
    #pragma unroll
    for (int off = 32; off > 0; off >>= 1)
        lsum += __shfl_down(lsum, off);
    if (lane == 0) sred[wave] = lsum;
    __syncthreads();
    if (tid == 0) {
        float t = (sred[0] + sred[1]) + (sred[2] + sred[3]);
        if (t != 0.0f) atomicAdd(out, t * (1.0f / 262144.0f));
    }
}

extern "C" void kernel_launch(void* const* d_in, const int* in_sizes, int n_in,
                              void* d_out, int out_size, void* d_ws, size_t ws_size,
                              hipStream_t stream) {
    const float* f1  = (const float*)d_in[0];
    const float* f2  = (const float*)d_in[1];
    const float* dp1 = (const float*)d_in[4];
    const float* dp2 = (const float*)d_in[5];
    const float* m1  = (const float*)d_in[6];
    const float* K1  = (const float*)d_in[8];
    const float* K2  = (const float*)d_in[9];
    const float* c1  = (const float*)d_in[10];
    const float* c2  = (const float*)d_in[11];

    float* out = (float*)d_out;
    hipMemsetAsync(out, 0, sizeof(float), stream);
    fused_kernel<<<NBLK, 256, 0, stream>>>(
        f1, f2, dp1, dp2, m1, K1, K2, c1, c2, out);
}

// Round 9
// 48.730 us; speedup vs baseline: 2.1934x; 1.1010x over previous
//
#include <hip/hip_runtime.h>

#define WW 512
#define HH 512
#define CC 64
#define HW (HH*WW)
#define PPB 128               // pixels per block
#define NBLK (HW/PPB)         // 2048 blocks

struct __align__(16) LItem {
    float4 ewA;   // element weights for sample A (f1_2 from f2)
    float4 ewB;   // element weights for sample B (f2_1 from f1)
    int4   o;     // a0, a1, b0, b1 row offsets (clamped in-range)
    float  wgt;
    int    pix;
    int    pad0, pad1;
};

__device__ __forceinline__ void invert3(const float* __restrict__ m, float* o) {
    float a = m[0], b = m[1], c = m[2];
    float d = m[3], e = m[4], f = m[5];
    float g = m[6], h = m[7], i = m[8];
    float C11 =  (e*i - f*h);
    float C12 = -(d*i - f*g);
    float C13 =  (d*h - e*g);
    float C21 = -(b*i - c*h);
    float C22 =  (a*i - c*g);
    float C23 = -(a*h - b*g);
    float C31 =  (b*f - c*e);
    float C32 = -(a*f - c*d);
    float C33 =  (a*e - b*d);
    float det = a*C11 + b*C12 + c*C13;
    float id = 1.0f / det;
    o[0] = C11*id; o[1] = C21*id; o[2] = C31*id;
    o[3] = C12*id; o[4] = C22*id; o[5] = C32*id;
    o[6] = C13*id; o[7] = C23*id; o[8] = C33*id;
}

__device__ __forceinline__ void reproj_pt(
    float px, float py, float d,
    const float Kinv[9],
    const float* __restrict__ cf, const float* __restrict__ ct,
    const float* __restrict__ Kt,
    float& ox, float& oy)
{
    float cx = Kinv[0]*px + Kinv[1]*py + Kinv[2];
    float cy = Kinv[3]*px + Kinv[4]*py + Kinv[5];
    float cz = Kinv[6]*px + Kinv[7]*py + Kinv[8];
    cx *= d; cy *= d; cz *= d;
    float wx = cf[0]*cx + cf[1]*cy + cf[2]*cz + cf[3];
    float wy = cf[4]*cx + cf[5]*cy + cf[6]*cz + cf[7];
    float wz = cf[8]*cx + cf[9]*cy + cf[10]*cz + cf[11];
    float qx = wx - ct[3], qy = wy - ct[7], qz = wz - ct[11];
    float ax = ct[0]*qx + ct[4]*qy + ct[8]*qz;
    float ay = ct[1]*qx + ct[5]*qy + ct[9]*qz;
    float az = ct[2]*qx + ct[6]*qy + ct[10]*qz;
    float p0 = Kt[0]*ax + Kt[1]*ay + Kt[2]*az;
    float p1 = Kt[3]*ax + Kt[4]*ay + Kt[5]*az;
    float p2 = Kt[6]*ax + Kt[7]*ay + Kt[8]*az;
    float zs = (fabsf(p2) > 1e-6f) ? p2 : 1e-6f;
    float u = p0 / zs;
    float v = p1 / zs;
    ox = u / 512.0f * 2.0f - 1.0f;
    oy = v / 512.0f * 2.0f - 1.0f;
}

// Bilinear state (verified absmax 0.0 in R4-R8): two clamped row offsets,
// 4 element-weights matched to elements (xc, xc+1) on rows y0, y0+1; OOB
// corners carry zero weight.
__device__ __forceinline__ void bilin_state(
    float lx, float ly, float4& ew, int& o0, int& o1)
{
    float xf = (lx + 1.0f) * 256.0f - 0.5f;
    float yf = (ly + 1.0f) * 256.0f - 0.5f;
    float x0 = floorf(xf), y0 = floorf(yf);
    float wx = xf - x0, wy = yf - y0;
    x0 = fminf(fmaxf(x0, -1e8f), 1e8f);
    y0 = fminf(fmaxf(y0, -1e8f), 1e8f);
    int x0i = (int)x0, y0i = (int)y0;

    float vx0 = (x0i >= 0 && x0i < WW) ? 1.0f : 0.0f;
    float vx1 = (x0i + 1 >= 0 && x0i + 1 < WW) ? 1.0f : 0.0f;
    float vy0 = (y0i >= 0 && y0i < HH) ? 1.0f : 0.0f;
    float vy1 = (y0i + 1 >= 0 && y0i + 1 < HH) ? 1.0f : 0.0f;
    float w00 = (1.0f - wx) * (1.0f - wy) * vx0 * vy0;
    float w10 = wx * (1.0f - wy) * vx1 * vy0;
    float w01 = (1.0f - wx) * wy * vx0 * vy1;
    float w11 = wx * wy * vx1 * vy1;

    int xc = min(max(x0i, 0), WW - 2);
    float e0r0 = (xc == x0i) ? w00 : ((xc == x0i + 1) ? w10 : 0.0f);
    float e1r0 = (xc + 1 == x0i + 1) ? w10 : ((xc + 1 == x0i) ? w00 : 0.0f);
    float e0r1 = (xc == x0i) ? w01 : ((xc == x0i + 1) ? w11 : 0.0f);
    float e1r1 = (xc + 1 == x0i + 1) ? w11 : ((xc + 1 == x0i) ? w01 : 0.0f);
    ew = make_float4(e0r0, e1r0, e0r1, e1r1);
    o0 = min(max(y0i, 0), HH - 1) * WW + xc;
    o1 = min(max(y0i + 1, 0), HH - 1) * WW + xc;
}

// Fused: 128 pixels/block (setup by tid<128, branchless corners) -> LDS
// compaction -> gather with lane = (item quad x 16 channels), 4-chunk
// channel loop unrolled (40 loads in flight, chunk working set fits XCD L2)
// -> block reduce -> one atomicAdd per block.
__global__ __launch_bounds__(256) void fused_kernel(
    const float* __restrict__ f1, const float* __restrict__ f2,
    const float* __restrict__ d1p, const float* __restrict__ d2p,
    const float* __restrict__ m1p,
    const float* __restrict__ K1, const float* __restrict__ K2,
    const float* __restrict__ cw1, const float* __restrict__ cw2,
    float* __restrict__ out)
{
    __shared__ LItem items[PPB];   // 8 KB
    __shared__ int nitems;
    __shared__ float sred[4];

    // XCD-chunked swizzle: contiguous pixel ranges land on one XCD's L2.
    int bid = (int)(blockIdx.x & 7) * (NBLK / 8) + (int)(blockIdx.x >> 3);

    int tid  = threadIdx.x;
    int wave = tid >> 6;
    int lane = tid & 63;
    bool active = tid < PPB;
    int pix  = bid * PPB + (tid & (PPB - 1));
    int j = pix & (WW - 1);
    int i = pix >> 9;

    if (tid == 0) nitems = 0;

    // ---------------- phase 1: setup (validated arithmetic) ----------------
    float wgt = 0.0f;
    float4 ewA; int a0 = 0, a1 = 0;
    float l21x = 0.0f, l21y = 0.0f;
    if (active) {
        float Ki1[9], Ki2[9];
        invert3(K1, Ki1);
        invert3(K2, Ki2);
        float px = j + 0.5f, py = i + 0.5f;

        float l12x, l12y;
        reproj_pt(px, py, d1p[pix], Ki1, cw1, cw2, K2, l12x, l12y);
        reproj_pt(px, py, d2p[pix], Ki2, cw2, cw1, K1, l21x, l21y);

        bilin_state(l12x, l12y, ewA, a0, a1);

        // l1_2_1: bilinear sample of the l2_1 field at l1_2 via exact corner
        // recompute from depth2. Branchless: clamped offsets always legal,
        // zero weights kill invalid corners (finite values * 0 == 0).
        int co[4] = {a0, a0 + 1, a1, a1 + 1};
        float cw[4] = {ewA.x, ewA.y, ewA.z, ewA.w};
        // issue the 4 depth loads up front (independent)
        float cd0 = d2p[co[0]], cd1 = d2p[co[1]];
        float cd2 = d2p[co[2]], cd3 = d2p[co[3]];
        float cds[4] = {cd0, cd1, cd2, cd3};
        float vx = 0.0f, vy = 0.0f;
        #pragma unroll
        for (int k = 0; k < 4; ++k) {
            int cj = co[k] & (WW - 1), ci = co[k] >> 9;
            float cxv, cyv;
            reproj_pt(cj + 0.5f, ci + 0.5f, cds[k], Ki2, cw2, cw1, K1, cxv, cyv);
            vx += cw[k] * cxv;
            vy += cw[k] * cyv;
        }
        float gx = (j + 0.5f) / 512.0f * 2.0f - 1.0f;
        float gy = (i + 0.5f) / 512.0f * 2.0f - 1.0f;
        float ddx = gx - vx, ddy = gy - vy;
        float dist = sqrtf(ddx * ddx + ddy * ddy);
        wgt = (dist < 0.0025f) ? m1p[pix] : 0.0f;
    }

    __syncthreads();   // nitems = 0 visible

    if (active && wgt != 0.0f) {
        float4 ewB; int b0, b1;
        bilin_state(l21x, l21y, ewB, b0, b1);
        int slot = atomicAdd(&nitems, 1);   // LDS atomic
        LItem s;
        s.ewA = ewA; s.ewB = ewB;
        s.o = make_int4(a0, a1, b0, b1);
        s.wgt = wgt; s.pix = pix; s.pad0 = 0; s.pad1 = 0;
        items[slot] = s;
    }
    __syncthreads();

    // -------- phase 2: lane = (item-quad, 16 channels); 4 channel chunks --------
    int n = nitems;
    int isub = lane >> 4;        // which of 4 items in the quad
    int c16  = lane & 15;        // channel within chunk

    float lsum = 0.0f;
    for (int base = wave * 4; base < n; base += 16) {
        int it = base + isub;
        bool has = it < n;
        int idx = has ? it : (n - 1);

        float4 eA = items[idx].ewA;
        float4 eB = items[idx].ewB;
        int4   o  = items[idx].o;
        float  w  = has ? items[idx].wgt : 0.0f;
        int    p  = items[idx].pix;

        float acc = 0.0f;
        #pragma unroll
        for (int chunk = 0; chunk < 4; ++chunk) {
            const float* F1 = f1 + (size_t)(chunk * 16 + c16) * HW;
            const float* F2 = f2 + (size_t)(chunk * 16 + c16) * HW;
            float a0v = F2[o.x], a1v = F2[o.x + 1];
            float a2v = F2[o.y], a3v = F2[o.y + 1];
            float b0v = F1[o.z], b1v = F1[o.z + 1];
            float b2v = F1[o.w], b3v = F1[o.w + 1];
            float p1v = F1[p],   p2v = F2[p];

            float s1 = eA.x * a0v + eA.y * a1v + eA.z * a2v + eA.w * a3v;
            float s2 = eB.x * b0v + eB.y * b1v + eB.z * b2v + eB.w * b3v;
            float e1 = p1v - s1;
            float e2 = p2v - s2;
            acc += e1 * e1 + e2 * e2;
        }
        lsum += w * acc;
    }

    // -------- reduce: wave shuffle -> LDS -> one atomic per block --------
    #pragma unroll
    for (int off = 32; off > 0; off >>= 1)
        lsum += __shfl_down(lsum, off);
    if (lane == 0) sred[wave] = lsum;
    __syncthreads();
    if (tid == 0) {
        float t = (sred[0] + sred[1]) + (sred[2] + sred[3]);
        if (t != 0.0f) atomicAdd(out, t * (1.0f / 262144.0f));
    }
}

extern "C" void kernel_launch(void* const* d_in, const int* in_sizes, int n_in,
                              void* d_out, int out_size, void* d_ws, size_t ws_size,
                              hipStream_t stream) {
    const float* f1  = (const float*)d_in[0];
    const float* f2  = (const float*)d_in[1];
    const float* dp1 = (const float*)d_in[4];
    const float* dp2 = (const float*)d_in[5];
    const float* m1  = (const float*)d_in[6];
    const float* K1  = (const float*)d_in[8];
    const float* K2  = (const float*)d_in[9];
    const float* c1  = (const float*)d_in[10];
    const float* c2  = (const float*)d_in[11];

    float* out = (float*)d_out;
    hipMemsetAsync(out, 0, sizeof(float), stream);
    fused_kernel<<<NBLK, 256, 0, stream>>>(
        f1, f2, dp1, dp2, m1, K1, K2, c1, c2, out);
}

// Round 10
// 48.686 us; speedup vs baseline: 2.1954x; 1.0009x over previous
//
#include <hip/hip_runtime.h>

#define WW 512
#define HH 512
#define CC 64
#define HW (HH*WW)
#define PPB 128               // pixels per block
#define NBLK (HW/PPB)         // 2048 blocks

// 4-byte-aligned float2 vector load: pairs (x, x+1) share a cache line;
// one dwordx2 instruction = one TA line-request instead of two.
typedef float f2v __attribute__((ext_vector_type(2), aligned(4)));

struct __align__(16) LItem {
    float4 ewA;   // element weights for sample A (f1_2 from f2)
    float4 ewB;   // element weights for sample B (f2_1 from f1)
    int4   o;     // a0, a1, b0, b1 row offsets (clamped in-range)
    float  wgt;
    int    pix;
    int    pad0, pad1;
};

__device__ __forceinline__ void invert3(const float* __restrict__ m, float* o) {
    float a = m[0], b = m[1], c = m[2];
    float d = m[3], e = m[4], f = m[5];
    float g = m[6], h = m[7], i = m[8];
    float C11 =  (e*i - f*h);
    float C12 = -(d*i - f*g);
    float C13 =  (d*h - e*g);
    float C21 = -(b*i - c*h);
    float C22 =  (a*i - c*g);
    float C23 = -(a*h - b*g);
    float C31 =  (b*f - c*e);
    float C32 = -(a*f - c*d);
    float C33 =  (a*e - b*d);
    float det = a*C11 + b*C12 + c*C13;
    float id = 1.0f / det;
    o[0] = C11*id; o[1] = C21*id; o[2] = C31*id;
    o[3] = C12*id; o[4] = C22*id; o[5] = C32*id;
    o[6] = C13*id; o[7] = C23*id; o[8] = C33*id;
}

__device__ __forceinline__ void reproj_pt(
    float px, float py, float d,
    const float Kinv[9],
    const float* __restrict__ cf, const float* __restrict__ ct,
    const float* __restrict__ Kt,
    float& ox, float& oy)
{
    float cx = Kinv[0]*px + Kinv[1]*py + Kinv[2];
    float cy = Kinv[3]*px + Kinv[4]*py + Kinv[5];
    float cz = Kinv[6]*px + Kinv[7]*py + Kinv[8];
    cx *= d; cy *= d; cz *= d;
    float wx = cf[0]*cx + cf[1]*cy + cf[2]*cz + cf[3];
    float wy = cf[4]*cx + cf[5]*cy + cf[6]*cz + cf[7];
    float wz = cf[8]*cx + cf[9]*cy + cf[10]*cz + cf[11];
    float qx = wx - ct[3], qy = wy - ct[7], qz = wz - ct[11];
    float ax = ct[0]*qx + ct[4]*qy + ct[8]*qz;
    float ay = ct[1]*qx + ct[5]*qy + ct[9]*qz;
    float az = ct[2]*qx + ct[6]*qy + ct[10]*qz;
    float p0 = Kt[0]*ax + Kt[1]*ay + Kt[2]*az;
    float p1 = Kt[3]*ax + Kt[4]*ay + Kt[5]*az;
    float p2 = Kt[6]*ax + Kt[7]*ay + Kt[8]*az;
    float zs = (fabsf(p2) > 1e-6f) ? p2 : 1e-6f;
    float u = p0 / zs;
    float v = p1 / zs;
    ox = u / 512.0f * 2.0f - 1.0f;
    oy = v / 512.0f * 2.0f - 1.0f;
}

// Bilinear state (verified absmax 0.0 in R4-R9): two clamped row offsets,
// 4 element-weights matched to elements (xc, xc+1) on rows y0, y0+1; OOB
// corners carry zero weight.
__device__ __forceinline__ void bilin_state(
    float lx, float ly, float4& ew, int& o0, int& o1)
{
    float xf = (lx + 1.0f) * 256.0f - 0.5f;
    float yf = (ly + 1.0f) * 256.0f - 0.5f;
    float x0 = floorf(xf), y0 = floorf(yf);
    float wx = xf - x0, wy = yf - y0;
    x0 = fminf(fmaxf(x0, -1e8f), 1e8f);
    y0 = fminf(fmaxf(y0, -1e8f), 1e8f);
    int x0i = (int)x0, y0i = (int)y0;

    float vx0 = (x0i >= 0 && x0i < WW) ? 1.0f : 0.0f;
    float vx1 = (x0i + 1 >= 0 && x0i + 1 < WW) ? 1.0f : 0.0f;
    float vy0 = (y0i >= 0 && y0i < HH) ? 1.0f : 0.0f;
    float vy1 = (y0i + 1 >= 0 && y0i + 1 < HH) ? 1.0f : 0.0f;
    float w00 = (1.0f - wx) * (1.0f - wy) * vx0 * vy0;
    float w10 = wx * (1.0f - wy) * vx1 * vy0;
    float w01 = (1.0f - wx) * wy * vx0 * vy1;
    float w11 = wx * wy * vx1 * vy1;

    int xc = min(max(x0i, 0), WW - 2);
    float e0r0 = (xc == x0i) ? w00 : ((xc == x0i + 1) ? w10 : 0.0f);
    float e1r0 = (xc + 1 == x0i + 1) ? w10 : ((xc + 1 == x0i) ? w00 : 0.0f);
    float e0r1 = (xc == x0i) ? w01 : ((xc == x0i + 1) ? w11 : 0.0f);
    float e1r1 = (xc + 1 == x0i + 1) ? w11 : ((xc + 1 == x0i) ? w01 : 0.0f);
    ew = make_float4(e0r0, e1r0, e0r1, e1r1);
    o0 = min(max(y0i, 0), HH - 1) * WW + xc;
    o1 = min(max(y0i + 1, 0), HH - 1) * WW + xc;
}

// Fused: 128 pixels/block (setup by tid<128, branchless corners, paired
// depth loads) -> LDS compaction -> gather with lane = (item quad x 16
// channels), 4-chunk channel loop, f2v pair loads (6 mem-ops per
// item-chunk) -> block reduce -> one atomicAdd per block.
__global__ __launch_bounds__(256) void fused_kernel(
    const float* __restrict__ f1, const float* __restrict__ f2,
    const float* __restrict__ d1p, const float* __restrict__ d2p,
    const float* __restrict__ m1p,
    const float* __restrict__ K1, const float* __restrict__ K2,
    const float* __restrict__ cw1, const float* __restrict__ cw2,
    float* __restrict__ out)
{
    __shared__ LItem items[PPB];   // 8 KB
    __shared__ int nitems;
    __shared__ float sred[4];

    // XCD-chunked swizzle: contiguous pixel ranges land on one XCD's L2.
    int bid = (int)(blockIdx.x & 7) * (NBLK / 8) + (int)(blockIdx.x >> 3);

    int tid  = threadIdx.x;
    int wave = tid >> 6;
    int lane = tid & 63;
    bool active = tid < PPB;
    int pix  = bid * PPB + (tid & (PPB - 1));
    int j = pix & (WW - 1);
    int i = pix >> 9;

    if (tid == 0) nitems = 0;

    // ---------------- phase 1: setup (validated arithmetic) ----------------
    float wgt = 0.0f;
    float4 ewA; int a0 = 0, a1 = 0;
    float l21x = 0.0f, l21y = 0.0f;
    if (active) {
        float Ki1[9], Ki2[9];
        invert3(K1, Ki1);
        invert3(K2, Ki2);
        float px = j + 0.5f, py = i + 0.5f;

        float l12x, l12y;
        reproj_pt(px, py, d1p[pix], Ki1, cw1, cw2, K2, l12x, l12y);
        reproj_pt(px, py, d2p[pix], Ki2, cw2, cw1, K1, l21x, l21y);

        bilin_state(l12x, l12y, ewA, a0, a1);

        // l1_2_1: bilinear sample of the l2_1 field at l1_2 via exact corner
        // recompute from depth2. Branchless; paired depth loads (same line).
        f2v cdr0 = *(const f2v*)(d2p + a0);   // depths at (a0, a0+1)
        f2v cdr1 = *(const f2v*)(d2p + a1);   // depths at (a1, a1+1)
        int co[4] = {a0, a0 + 1, a1, a1 + 1};
        float cw[4] = {ewA.x, ewA.y, ewA.z, ewA.w};
        float cds[4] = {cdr0.x, cdr0.y, cdr1.x, cdr1.y};
        float vx = 0.0f, vy = 0.0f;
        #pragma unroll
        for (int k = 0; k < 4; ++k) {
            int cj = co[k] & (WW - 1), ci = co[k] >> 9;
            float cxv, cyv;
            reproj_pt(cj + 0.5f, ci + 0.5f, cds[k], Ki2, cw2, cw1, K1, cxv, cyv);
            vx += cw[k] * cxv;
            vy += cw[k] * cyv;
        }
        float gx = (j + 0.5f) / 512.0f * 2.0f - 1.0f;
        float gy = (i + 0.5f) / 512.0f * 2.0f - 1.0f;
        float ddx = gx - vx, ddy = gy - vy;
        float dist = sqrtf(ddx * ddx + ddy * ddy);
        wgt = (dist < 0.0025f) ? m1p[pix] : 0.0f;
    }

    __syncthreads();   // nitems = 0 visible

    if (active && wgt != 0.0f) {
        float4 ewB; int b0, b1;
        bilin_state(l21x, l21y, ewB, b0, b1);
        int slot = atomicAdd(&nitems, 1);   // LDS atomic
        LItem s;
        s.ewA = ewA; s.ewB = ewB;
        s.o = make_int4(a0, a1, b0, b1);
        s.wgt = wgt; s.pix = pix; s.pad0 = 0; s.pad1 = 0;
        items[slot] = s;
    }
    __syncthreads();

    // -------- phase 2: lane = (item-quad, 16 channels); 4 channel chunks --------
    int n = nitems;
    int isub = lane >> 4;        // which of 4 items in the quad
    int c16  = lane & 15;        // channel within chunk

    float lsum = 0.0f;
    for (int base = wave * 4; base < n; base += 16) {
        int it = base + isub;
        bool has = it < n;
        int idx = has ? it : (n - 1);

        float4 eA = items[idx].ewA;
        float4 eB = items[idx].ewB;
        int4   o  = items[idx].o;
        float  w  = has ? items[idx].wgt : 0.0f;
        int    p  = items[idx].pix;

        float acc = 0.0f;
        #pragma unroll
        for (int chunk = 0; chunk < 4; ++chunk) {
            const float* F1 = f1 + (size_t)(chunk * 16 + c16) * HW;
            const float* F2 = f2 + (size_t)(chunk * 16 + c16) * HW;
            f2v a01 = *(const f2v*)(F2 + o.x);   // f1_2 corners, row y0
            f2v a23 = *(const f2v*)(F2 + o.y);   // row y0+1
            f2v b01 = *(const f2v*)(F1 + o.z);   // f2_1 corners, row y0
            f2v b23 = *(const f2v*)(F1 + o.w);   // row y0+1
            float p1v = F1[p],   p2v = F2[p];

            float s1 = eA.x * a01.x + eA.y * a01.y + eA.z * a23.x + eA.w * a23.y;
            float s2 = eB.x * b01.x + eB.y * b01.y + eB.z * b23.x + eB.w * b23.y;
            float e1 = p1v - s1;
            float e2 = p2v - s2;
            acc += e1 * e1 + e2 * e2;
        }
        lsum += w * acc;
    }

    // -------- reduce: wave shuffle -> LDS -> one atomic per block --------
    #pragma unroll
    for (int off = 32; off > 0; off >>= 1)
        lsum += __shfl_down(lsum, off);
    if (lane == 0) sred[wave] = lsum;
    __syncthreads();
    if (tid == 0) {
        float t = (sred[0] + sred[1]) + (sred[2] + sred[3]);
        if (t != 0.0f) atomicAdd(out, t * (1.0f / 262144.0f));
    }
}

extern "C" void kernel_launch(void* const* d_in, const int* in_sizes, int n_in,
                              void* d_out, int out_size, void* d_ws, size_t ws_size,
                              hipStream_t stream) {
    const float* f1  = (const float*)d_in[0];
    const float* f2  = (const float*)d_in[1];
    const float* dp1 = (const float*)d_in[4];
    const float* dp2 = (const float*)d_in[5];
    const float* m1  = (const float*)d_in[6];
    const float* K1  = (const float*)d_in[8];
    const float* K2  = (const float*)d_in[9];
    const float* c1  = (const float*)d_in[10];
    const float* c2  = (const float*)d_in[11];

    float* out = (float*)d_out;
    hipMemsetAsync(out, 0, sizeof(float), stream);
    fused_kernel<<<NBLK, 256, 0, stream>>>(
        f1, f2, dp1, dp2, m1, K1, K2, c1, c2, out);
}